// Round 2
// baseline (6333.127 us; speedup 1.0000x reference)
//
#include <hip/hip_runtime.h>
#include <hip/hip_bf16.h>

#define NROWS 32768
#define DIM 1024
#define NCLS 10

static constexpr size_t DD = (size_t)DIM * DIM;

// ---------------- small setup kernels ----------------

__global__ void init_small_kernel(int* counts, int* cursor, float* logdets) {
    int t = threadIdx.x;
    if (t < NCLS) { counts[t] = 0; cursor[t] = 0; }
    if (t < 32) logdets[t] = 0.f;
}

__global__ void hist_kernel(const int* __restrict__ lab, int* __restrict__ counts) {
    __shared__ int h[NCLS];
    if (threadIdx.x < NCLS) h[threadIdx.x] = 0;
    __syncthreads();
    int stride = gridDim.x * blockDim.x;
    for (int i = blockIdx.x * blockDim.x + threadIdx.x; i < NROWS; i += stride)
        atomicAdd(&h[lab[i]], 1);
    __syncthreads();
    if (threadIdx.x < NCLS) atomicAdd(&counts[threadIdx.x], h[threadIdx.x]);
}

__global__ void offs_kernel(const int* __restrict__ counts, int* __restrict__ offs) {
    if (threadIdx.x == 0 && blockIdx.x == 0) {
        int s = 0;
        for (int j = 0; j < NCLS; ++j) { offs[j] = s; s += counts[j]; }
    }
}

__global__ void scatter_kernel(const int* __restrict__ lab, const int* __restrict__ offs,
                               int* __restrict__ cursor, int* __restrict__ order) {
    int stride = gridDim.x * blockDim.x;
    for (int i = blockIdx.x * blockDim.x + threadIdx.x; i < NROWS; i += stride) {
        int j = lab[i];
        int p = atomicAdd(&cursor[j], 1);
        order[offs[j] + p] = i;
    }
}

// ---------------- per-class Gram kernel ----------------
// 128x128 tile per block, 8x8 per thread as four 64x64 quadrants.
// Round-2 fix: __launch_bounds__(256, 2) raises the VGPR cap so the 64-float
// accumulator stays in architectural VGPRs (round-1 got VGPR_Count=64 ->
// AGPR/spill juggling, FMA-issue duty only 48% of VALU).
// grid: (36 lower 128-tiles, 20 matrices). 16-row K chunks staged in LDS.

__global__ __launch_bounds__(256, 2) void gram_kernel(
        const float* __restrict__ Z, const float* __restrict__ Zb,
        const int* __restrict__ order, const int* __restrict__ counts,
        const int* __restrict__ offs, float* __restrict__ chol) {
    const int m = blockIdx.y;            // 0..19
    const int x = blockIdx.x;            // 0..35 (lower-triangular 128-tile id)
    int ti = 0;
    while ((ti + 1) * (ti + 2) / 2 <= x) ++ti;
    const int tj = x - ti * (ti + 1) / 2;
    const int cls = m % NCLS;
    const float* __restrict__ src = (m < NCLS) ? Z : Zb;
    float* __restrict__ G = chol + (size_t)(2 + m) * DD;
    const int cnt = counts[cls];
    const int base = offs[cls];

    __shared__ float As[16][132];
    __shared__ float Bs[16][132];

    const int t = threadIdx.x;
    const int lrow = t >> 4;        // staging k-row 0..15
    const int lf4 = t & 15;         // staging float4 slot
    const int r0 = (t >> 4) * 4;    // quadrant-local row offset 0..60
    const int c0 = (t & 15) * 4;    // quadrant-local col offset 0..60

    float acc[8][8] = {};           // [0..3]=rows r0+i, [4..7]=rows 64+r0+i

    const int nch = (cnt + 15) >> 4;
    for (int ch = 0; ch < nch; ++ch) {
        int rr = ch * 16 + lrow;
        float4 a0v = make_float4(0.f, 0.f, 0.f, 0.f);
        float4 a1v = make_float4(0.f, 0.f, 0.f, 0.f);
        float4 b0v = make_float4(0.f, 0.f, 0.f, 0.f);
        float4 b1v = make_float4(0.f, 0.f, 0.f, 0.f);
        if (rr < cnt) {
            int ridx = order[base + rr];
            const float* rowp = src + (size_t)ridx * DIM;
            a0v = *(const float4*)(rowp + ti * 128 + lf4 * 4);
            a1v = *(const float4*)(rowp + ti * 128 + 64 + lf4 * 4);
            b0v = *(const float4*)(rowp + tj * 128 + lf4 * 4);
            b1v = *(const float4*)(rowp + tj * 128 + 64 + lf4 * 4);
        }
        __syncthreads();
        *(float4*)&As[lrow][lf4 * 4] = a0v;
        *(float4*)&As[lrow][64 + lf4 * 4] = a1v;
        *(float4*)&Bs[lrow][lf4 * 4] = b0v;
        *(float4*)&Bs[lrow][64 + lf4 * 4] = b1v;
        __syncthreads();
#pragma unroll
        for (int k = 0; k < 16; ++k) {
            float4 a0 = *(const float4*)&As[k][r0];
            float4 a1 = *(const float4*)&As[k][64 + r0];
            float4 b0 = *(const float4*)&Bs[k][c0];
            float4 b1 = *(const float4*)&Bs[k][64 + c0];
            float a_[8] = {a0.x, a0.y, a0.z, a0.w, a1.x, a1.y, a1.z, a1.w};
            float b_[8] = {b0.x, b0.y, b0.z, b0.w, b1.x, b1.y, b1.z, b1.w};
#pragma unroll
            for (int i = 0; i < 8; ++i)
#pragma unroll
                for (int j = 0; j < 8; ++j)
                    acc[i][j] = fmaf(a_[i], b_[j], acc[i][j]);
        }
    }

#pragma unroll
    for (int ih = 0; ih < 2; ++ih)
#pragma unroll
        for (int i = 0; i < 4; ++i) {
            int gr = ti * 128 + ih * 64 + r0 + i;
#pragma unroll
            for (int jh = 0; jh < 2; ++jh) {
                float4 v = make_float4(acc[ih * 4 + i][jh * 4 + 0],
                                       acc[ih * 4 + i][jh * 4 + 1],
                                       acc[ih * 4 + i][jh * 4 + 2],
                                       acc[ih * 4 + i][jh * 4 + 3]);
                *(float4*)&G[(size_t)gr * DIM + tj * 128 + jh * 64 + c0] = v;
            }
        }
    if (ti != tj) {
#pragma unroll
        for (int ih = 0; ih < 2; ++ih)
#pragma unroll
            for (int i = 0; i < 4; ++i)
#pragma unroll
                for (int jh = 0; jh < 2; ++jh)
#pragma unroll
                    for (int j = 0; j < 4; ++j)
                        G[(size_t)(tj * 128 + jh * 64 + c0 + j) * DIM
                          + ti * 128 + ih * 64 + r0 + i] = acc[ih * 4 + i][jh * 4 + j];
    }
}

// ---------------- build M = I + c*G matrices (fused, single pass) ----------

__global__ __launch_bounds__(256) void build_kernel(float* __restrict__ chol,
                                                    const int* __restrict__ counts) {
    size_t e = (size_t)blockIdx.x * 256 + threadIdx.x;
    int a = (int)(e >> 10), b = (int)(e & 1023);
    float diag = (a == b) ? 1.f : 0.f;
    float gz[NCLS], gzb[NCLS];
    float sz = 0.f, szb = 0.f;
#pragma unroll
    for (int j = 0; j < NCLS; ++j) { gz[j] = chol[(size_t)(2 + j) * DD + e];  sz += gz[j]; }
#pragma unroll
    for (int j = 0; j < NCLS; ++j) { gzb[j] = chol[(size_t)(12 + j) * DD + e]; szb += gzb[j]; }
    chol[e]      = diag + (1.f / 16.f) * sz;    // d/(n*eps) = 1/16
    chol[DD + e] = diag + (1.f / 16.f) * szb;
#pragma unroll
    for (int j = 0; j < NCLS; ++j) {
        float c = (float)counts[j];
        float scal = 2048.f / (c + 1e-8f);       // d/(trPi*eps)
        chol[(size_t)(2 + j) * DD + e]  = diag + scal * gz[j];
        chol[(size_t)(12 + j) * DD + e] = diag + scal * gzb[j];
        chol[(size_t)(22 + j) * DD + e] = diag + (1024.f / c) * (gz[j] + gzb[j]); // d/(n2*eps)
    }
}

// ---------------- fused Cholesky stage kernel ----------------
// ONE dispatch per NB=64 stage (was diag+trsm+syrk = 3). Key insight: after a
// stage, the factored diag block and trsm'd panel are NEVER read again (only
// the logdet is). So every trailing-tile block redundantly re-factors the
// 64x64 diag in its own LDS (bitwise identical across blocks: same code, same
// inputs) and redundantly trsm's exactly the two 64-row panel slices it needs
// -- straight into transposed LDS, no global round-trip -- then applies its
// syrk update. Reads (diag+panel pre-state) and writes (trailing tiles at
// rows/cols >= k0+64, logdet atomic) are disjoint: no races, no grid sync.
// grid: (nt*(nt+1)/2 tiles [or 1 when nt==0], 32 matrices).

__global__ __launch_bounds__(256, 2) void stage_kernel(float* __restrict__ chol,
                                                       float* __restrict__ logdets,
                                                       int k0, int nt) {
    const int m = blockIdx.y;
    float* __restrict__ A = chol + (size_t)m * DD;
    const int t = threadIdx.x;

    __shared__ float Ld[64][68];
    __shared__ float rd[64];
    __shared__ float red[64];
    __shared__ float PiT[64][68];   // trsm'd slice bi, [k][r]
    __shared__ float PjT[64][68];   // trsm'd slice bj, [k][r]

    // ---- phase 1: load + factor diag block in LDS (redundant per block) ----
    for (int e = t; e < 1024; e += 256) {
        int r = e >> 4, q = e & 15;
        *(float4*)&Ld[r][q * 4] = *(const float4*)(A + (size_t)(k0 + r) * DIM + k0 + q * 4);
    }
    __syncthreads();

    for (int kk = 0; kk < 64; ++kk) {
        if (t == 0) Ld[kk][kk] = sqrtf(Ld[kk][kk]);
        __syncthreads();
        if (t > kk && t < 64) Ld[t][kk] /= Ld[kk][kk];
        __syncthreads();
        for (int e = ((kk + 1) << 6) + t; e < 4096; e += 256) {
            int r = e >> 6, c = e & 63;
            if (c > kk && c <= r) Ld[r][c] -= Ld[r][kk] * Ld[c][kk];
        }
        __syncthreads();
    }

    // block x==0 of each matrix owns the logdet contribution
    if (blockIdx.x == 0) {
        if (t < 64) red[t] = logf(Ld[t][t]);
        __syncthreads();
        if (t == 0) {
            float s = 0.f;
            for (int i = 0; i < 64; ++i) s += red[i];
            atomicAdd(&logdets[m], 2.f * s);
        }
    }
    if (nt == 0) return;   // last stage: logdet only

    // ---- phase 2: redundant trsm of the two panel slices this tile needs ----
    int x = blockIdx.x;
    int bi = 0;
    while ((bi + 1) * (bi + 2) / 2 <= x) ++bi;
    const int bj = x - bi * (bi + 1) / 2;
    const int st = k0 + 64;

    if (t < 64) rd[t] = 1.f / Ld[t][t];
    __syncthreads();

    const int nact = (bi != bj) ? 128 : 64;
    if (t < nact) {
        const int bsel = (t < 64) ? bi : bj;
        const int lane = t & 63;
        const int r = st + bsel * 64 + lane;

        float xr[64];
        float4* xv = (float4*)xr;
        const float4* sp = (const float4*)(A + (size_t)r * DIM + k0);
#pragma unroll
        for (int u = 0; u < 16; ++u) xv[u] = sp[u];

#pragma unroll
        for (int kk = 0; kk < 64; ++kk) {
            float s0 = 0.f, s1 = 0.f;
            const float* lrow = &Ld[kk][0];
#pragma unroll
            for (int u = 0; u + 7 < kk; u += 8) {
                float4 l0 = *(const float4*)(lrow + u);
                float4 l1 = *(const float4*)(lrow + u + 4);
                s0 += xr[u] * l0.x + xr[u + 1] * l0.y + xr[u + 2] * l0.z + xr[u + 3] * l0.w;
                s1 += xr[u + 4] * l1.x + xr[u + 5] * l1.y + xr[u + 6] * l1.z + xr[u + 7] * l1.w;
            }
#pragma unroll
            for (int u = kk & ~7; u < kk; ++u) s0 += xr[u] * lrow[u];
            float v = (xr[kk] - (s0 + s1)) * rd[kk];
            xr[kk] = v;
            if (t < 64) PiT[kk][lane] = v;   // transposed store: conflict-free
            else        PjT[kk][lane] = v;
        }
    }
    __syncthreads();

    // ---- phase 3: syrk update of this trailing tile ----
    float (*Pj)[68] = (bj == bi) ? PiT : PjT;
    const int r0 = (t >> 4) * 4;
    const int c0 = (t & 15) * 4;
    float acc[4][4] = {};
#pragma unroll
    for (int u = 0; u < 64; ++u) {
        float4 a4 = *(const float4*)&PiT[u][r0];
        float4 b4 = *(const float4*)&Pj[u][c0];
        float a_[4] = {a4.x, a4.y, a4.z, a4.w};
        float b_[4] = {b4.x, b4.y, b4.z, b4.w};
#pragma unroll
        for (int i = 0; i < 4; ++i)
#pragma unroll
            for (int j = 0; j < 4; ++j)
                acc[i][j] = fmaf(a_[i], b_[j], acc[i][j]);
    }

    const int ra = st + bi * 64, ca = st + bj * 64;
#pragma unroll
    for (int i = 0; i < 4; ++i) {
        float* p = A + (size_t)(ra + r0 + i) * DIM + ca + c0;
        float4 v = *(const float4*)p;
        v.x -= acc[i][0]; v.y -= acc[i][1]; v.z -= acc[i][2]; v.w -= acc[i][3];
        *(float4*)p = v;
    }
}

// ---------------- final scalar combine ----------------

__global__ void finalize_kernel(const float* __restrict__ logdets,
                                const int* __restrict__ counts,
                                unsigned int* __restrict__ out) {
    if (threadIdx.x == 0 && blockIdx.x == 0) {
        const float nf = 32768.f;
        float compZ = 0.f, compH = 0.f, pc = 0.f;
        for (int j = 0; j < NCLS; ++j) {
            float c = (float)counts[j];
            float trPi = c + 1e-8f;
            compZ += trPi / (2.f * nf) * logdets[2 + j];
            compH += trPi / (2.f * nf) * logdets[12 + j];
            pc += -(logdets[22 + j] * 0.5f
                    - trPi / (4.f * c) * (logdets[2 + j] + logdets[12 + j]));
        }
        float loss_z = -(logdets[0] * 0.5f - compZ);
        float loss_h = -(logdets[1] * 0.5f - compH);
        float v = loss_z + loss_h + pc;
        unsigned int x = __float_as_uint(v);
        unsigned int r = (x + 0x7fffu + ((x >> 16) & 1u)) >> 16;  // rne bf16
        out[0] = (r << 16) | r;
    }
}

// ---------------- launch ----------------

extern "C" void kernel_launch(void* const* d_in, const int* in_sizes, int n_in,
                              void* d_out, int out_size, void* d_ws, size_t ws_size,
                              hipStream_t stream) {
    const float* Z  = (const float*)d_in[0];
    const float* Zb = (const float*)d_in[1];
    const int* lab  = (const int*)d_in[2];

    float* chol = (float*)d_ws;                       // 32 matrices, 4 MiB each
    const size_t CHOL_FLOATS = 32ull * 1024 * 1024;
    int* order   = (int*)(chol + CHOL_FLOATS);        // 32768
    int* counts  = order + NROWS;
    int* cursor  = counts + 16;
    int* offs    = cursor + 16;
    float* logdets = (float*)(offs + 16);             // 32

    init_small_kernel<<<1, 64, 0, stream>>>(counts, cursor, logdets);
    hist_kernel<<<128, 256, 0, stream>>>(lab, counts);
    offs_kernel<<<1, 64, 0, stream>>>(counts, offs);
    scatter_kernel<<<128, 256, 0, stream>>>(lab, offs, cursor, order);

    // 36 lower-triangular 128x128 tiles (nt=8), 20 matrices
    gram_kernel<<<dim3(36, 20), 256, 0, stream>>>(Z, Zb, order, counts, offs, chol);

    build_kernel<<<4096, 256, 0, stream>>>(chol, counts);

    // fused Cholesky: one dispatch per 64-wide stage (16 total, was 47)
    for (int s = 0; s < 16; ++s) {
        const int k0 = s * 64;
        const int nt = 15 - s;
        const int T = (nt > 0) ? nt * (nt + 1) / 2 : 1;
        stage_kernel<<<dim3(T, 32), 256, 0, stream>>>(chol, logdets, k0, nt);
    }

    finalize_kernel<<<1, 64, 0, stream>>>(logdets, counts, (unsigned int*)d_out);
}

// Round 3
// 2567.937 us; speedup vs baseline: 2.4662x; 2.4662x over previous
//
#include <hip/hip_runtime.h>
#include <hip/hip_bf16.h>

#define NROWS 32768
#define DIM 1024
#define NCLS 10
#define PSTRIDE 33088   // 32768 + 10*32 pad, multiple of 64; u16 rows stay 16B-aligned
#define NPOS 33088

static constexpr size_t DD = (size_t)DIM * DIM;

typedef _Float16 f16x8 __attribute__((ext_vector_type(8)));
typedef float f32x4 __attribute__((ext_vector_type(4)));
typedef unsigned short ushort8 __attribute__((ext_vector_type(8)));

// ---------------- small setup kernels ----------------

__global__ void init_small_kernel(int* counts, int* cursor, float* logdets) {
    int t = threadIdx.x;
    if (t < NCLS) { counts[t] = 0; cursor[t] = 0; }
    if (t < 32) logdets[t] = 0.f;
}

__global__ void hist_kernel(const int* __restrict__ lab, int* __restrict__ counts) {
    __shared__ int h[NCLS];
    if (threadIdx.x < NCLS) h[threadIdx.x] = 0;
    __syncthreads();
    int stride = gridDim.x * blockDim.x;
    for (int i = blockIdx.x * blockDim.x + threadIdx.x; i < NROWS; i += stride)
        atomicAdd(&h[lab[i]], 1);
    __syncthreads();
    if (threadIdx.x < NCLS) atomicAdd(&counts[threadIdx.x], h[threadIdx.x]);
}

// 32-aligned class segments so every 8-sample group in Ht/Lt is 16B-aligned
__global__ void offs_kernel(const int* __restrict__ counts, int* __restrict__ offs) {
    if (threadIdx.x == 0 && blockIdx.x == 0) {
        int s = 0;
        for (int j = 0; j < NCLS; ++j) { offs[j] = s; s += (counts[j] + 31) & ~31; }
    }
}

__global__ void scatter_kernel(const int* __restrict__ lab, const int* __restrict__ offs,
                               int* __restrict__ cursor, int* __restrict__ order) {
    int stride = gridDim.x * blockDim.x;
    for (int i = blockIdx.x * blockDim.x + threadIdx.x; i < NROWS; i += stride) {
        int j = lab[i];
        int p = atomicAdd(&cursor[j], 1);
        order[offs[j] + p] = i;
    }
}

// ---------------- pre-convert: permute + transpose + f16 hi/lo split -------
// Ht[f][p] = f16(Z[order[p]][f]), Lt[f][p] = f16(residual). Pad positions
// (order[p] == -1) become zeros -> contribute nothing to the Gram.
// Block: 64 positions x 64 features, LDS-packed u32 (hi | lo<<16) transpose.

__global__ __launch_bounds__(256) void preconv_kernel(
        const float* __restrict__ src, const int* __restrict__ order,
        unsigned short* __restrict__ Ht, unsigned short* __restrict__ Lt) {
    const int P0 = blockIdx.x * 64;
    const int F0 = blockIdx.y * 64;
    const int t = threadIdx.x;

    __shared__ unsigned int LDSp[64][65];   // [feature][position], 65 kills write conflicts

    const int pp = t >> 2, qq = t & 3;
    const int r = order[P0 + pp];
    const float* rowp = (r >= 0) ? (src + (size_t)r * DIM + F0) : nullptr;
#pragma unroll
    for (int k = 0; k < 4; ++k) {
        float4 v = make_float4(0.f, 0.f, 0.f, 0.f);
        if (r >= 0) v = *(const float4*)(rowp + qq * 16 + k * 4);
        float x[4] = {v.x, v.y, v.z, v.w};
#pragma unroll
        for (int e = 0; e < 4; ++e) {
            _Float16 h = (_Float16)x[e];
            _Float16 lo = (_Float16)(x[e] - (float)h);
            unsigned int hb = __builtin_bit_cast(unsigned short, h);
            unsigned int lb = __builtin_bit_cast(unsigned short, lo);
            LDSp[qq * 16 + k * 4 + e][pp] = hb | (lb << 16);
        }
    }
    __syncthreads();

#pragma unroll
    for (int u = 0; u < 2; ++u) {
        int task = t + 256 * u;
        int ck = task & 7, f = task >> 3;      // 8 p-chunks x 64 features
        ushort8 hv, lv;
#pragma unroll
        for (int i = 0; i < 8; ++i) {
            unsigned int w = LDSp[f][ck * 8 + i];
            hv[i] = (unsigned short)(w & 0xffffu);
            lv[i] = (unsigned short)(w >> 16);
        }
        size_t ob = (size_t)(F0 + f) * PSTRIDE + P0 + ck * 8;
        *(ushort8*)(Ht + ob) = hv;
        *(ushort8*)(Lt + ob) = lv;
    }
}

// ---------------- MFMA Gram kernel (f16 hi/lo split) ----------------
// G = S^T S via  H^T H + H^T L + L^T H  (drop L^T L, rel err ~2^-22).
// 128x128 tile per block, 4 waves own 64x64 quadrants, 16x16x32 MFMA.
// LDS staged in exact fragment order: lane l reads 16B at l*16 (conflict-free).
// K-permutation invariance: A and B staging identical -> hw k-layout irrelevant.
// grid: (36 lower 128-tiles, 10 classes). Launched once per source matrix.

__global__ __launch_bounds__(256, 2) void gram_mfma_kernel(
        const unsigned short* __restrict__ Ht, const unsigned short* __restrict__ Lt,
        const int* __restrict__ counts, const int* __restrict__ offs,
        float* __restrict__ Gbase) {
    const int cls = blockIdx.y;
    const int x = blockIdx.x;
    int ti = 0;
    while ((ti + 1) * (ti + 2) / 2 <= x) ++ti;
    const int tj = x - ti * (ti + 1) / 2;
    float* __restrict__ G = Gbase + (size_t)cls * DD;
    const int cnt = counts[cls];
    const int base = offs[cls];
    const int nch = (cnt + 31) >> 5;   // padded positions are zero -> safe

    // plane layout: [fb(8)][g(4)][fl(16)][8 samples] u16 = 4096 u16 = 8KB each
    __shared__ unsigned short AH[4096], AL[4096], BH[4096], BL[4096];

    const int t = threadIdx.x;
    const int l = t & 63;
    const int w = t >> 6;
    const int wr = w >> 1, wc = w & 1;     // 64x64 quadrant of the 128x128 tile

    f32x4 acc[4][4] = {};

    for (int ch = 0; ch < nch; ++ch) {
        const size_t p0 = (size_t)base + ch * 32;
        // ---- stage: 4 tasks/thread; g fastest -> 64B-coalesced global reads
#pragma unroll
        for (int u = 0; u < 4; ++u) {
            int task = t + 256 * u;
            int g = task & 3, fl = (task >> 2) & 15, fb = (task >> 6) & 7, sl = task >> 9;
            int f = (sl ? tj : ti) * 128 + fb * 16 + fl;
            size_t gb = (size_t)f * PSTRIDE + p0 + g * 8;
            ushort8 hv = *(const ushort8*)(Ht + gb);
            ushort8 lv = *(const ushort8*)(Lt + gb);
            int off = fb * 512 + (g * 16 + fl) * 8;
            *(ushort8*)((sl ? BH : AH) + off) = hv;
            *(ushort8*)((sl ? BL : AL) + off) = lv;
        }
        __syncthreads();

        // ---- fragments: lane-consecutive 16B reads
        f16x8 ah[4], al[4], bh[4], bl[4];
#pragma unroll
        for (int p = 0; p < 4; ++p) {
            ah[p] = *(const f16x8*)(AH + (wr * 4 + p) * 512 + l * 8);
            al[p] = *(const f16x8*)(AL + (wr * 4 + p) * 512 + l * 8);
        }
#pragma unroll
        for (int q = 0; q < 4; ++q) {
            bh[q] = *(const f16x8*)(BH + (wc * 4 + q) * 512 + l * 8);
            bl[q] = *(const f16x8*)(BL + (wc * 4 + q) * 512 + l * 8);
        }
#pragma unroll
        for (int p = 0; p < 4; ++p)
#pragma unroll
            for (int q = 0; q < 4; ++q) {
                acc[p][q] = __builtin_amdgcn_mfma_f32_16x16x32_f16(ah[p], bh[q], acc[p][q], 0, 0, 0);
                acc[p][q] = __builtin_amdgcn_mfma_f32_16x16x32_f16(ah[p], bl[q], acc[p][q], 0, 0, 0);
                acc[p][q] = __builtin_amdgcn_mfma_f32_16x16x32_f16(al[p], bh[q], acc[p][q], 0, 0, 0);
            }
        __syncthreads();
    }

    // ---- epilogue: C/D layout col=lane&15, row=(lane>>4)*4+reg (m89-verified)
    const int rowb = ti * 128 + wr * 64;
    const int colb = tj * 128 + wc * 64;
    const int lr = (l >> 4) * 4, lc = l & 15;
#pragma unroll
    for (int p = 0; p < 4; ++p)
#pragma unroll
        for (int q = 0; q < 4; ++q)
#pragma unroll
            for (int r = 0; r < 4; ++r) {
                int gr = rowb + p * 16 + lr + r;
                int gc = colb + q * 16 + lc;
                G[(size_t)gr * DIM + gc] = acc[p][q][r];
                if (ti != tj) G[(size_t)gc * DIM + gr] = acc[p][q][r];
            }
}

// ---------------- build M = I + c*G matrices (fused, single pass) ----------

__global__ __launch_bounds__(256) void build_kernel(float* __restrict__ chol,
                                                    const int* __restrict__ counts) {
    size_t e = (size_t)blockIdx.x * 256 + threadIdx.x;
    int a = (int)(e >> 10), b = (int)(e & 1023);
    float diag = (a == b) ? 1.f : 0.f;
    float gz[NCLS], gzb[NCLS];
    float sz = 0.f, szb = 0.f;
#pragma unroll
    for (int j = 0; j < NCLS; ++j) { gz[j] = chol[(size_t)(2 + j) * DD + e];  sz += gz[j]; }
#pragma unroll
    for (int j = 0; j < NCLS; ++j) { gzb[j] = chol[(size_t)(12 + j) * DD + e]; szb += gzb[j]; }
    chol[e]      = diag + (1.f / 16.f) * sz;    // d/(n*eps) = 1/16
    chol[DD + e] = diag + (1.f / 16.f) * szb;
#pragma unroll
    for (int j = 0; j < NCLS; ++j) {
        float c = (float)counts[j];
        float scal = 2048.f / (c + 1e-8f);       // d/(trPi*eps)
        chol[(size_t)(2 + j) * DD + e]  = diag + scal * gz[j];
        chol[(size_t)(12 + j) * DD + e] = diag + scal * gzb[j];
        chol[(size_t)(22 + j) * DD + e] = diag + (1024.f / c) * (gz[j] + gzb[j]); // d/(n2*eps)
    }
}

// ---------------- batched Cholesky: diag / trsm / syrk per NB=64 step ------
// (round-0 proven structure, reverted verbatim)

__global__ __launch_bounds__(256) void diag_kernel(float* __restrict__ chol,
                                                   float* __restrict__ logdets,
                                                   int k0) {
    const int m = blockIdx.x;
    float* __restrict__ A = chol + (size_t)m * DD;
    __shared__ float Ld[64][68];
    __shared__ float red[64];
    const int t = threadIdx.x;

    for (int e = t; e < 1024; e += 256) {
        int r = e >> 4, q = e & 15;
        *(float4*)&Ld[r][q * 4] = *(const float4*)(A + (size_t)(k0 + r) * DIM + k0 + q * 4);
    }
    __syncthreads();

    for (int kk = 0; kk < 64; ++kk) {
        if (t == 0) Ld[kk][kk] = sqrtf(Ld[kk][kk]);
        __syncthreads();
        if (t > kk && t < 64) Ld[t][kk] /= Ld[kk][kk];
        __syncthreads();
        for (int e = ((kk + 1) << 6) + t; e < 4096; e += 256) {
            int r = e >> 6, c = e & 63;
            if (c > kk && c <= r) Ld[r][c] -= Ld[r][kk] * Ld[c][kk];
        }
        __syncthreads();
    }

    if (t < 64) red[t] = logf(Ld[t][t]);
    __syncthreads();
    if (t == 0) {
        float s = 0.f;
        for (int i = 0; i < 64; ++i) s += red[i];
        atomicAdd(&logdets[m], 2.f * s);
    }

    for (int e = t; e < 1024; e += 256) {
        int r = e >> 4, q = e & 15;
        *(float4*)(A + (size_t)(k0 + r) * DIM + k0 + q * 4) = *(const float4*)&Ld[r][q * 4];
    }
}

__global__ __launch_bounds__(256) void trsm_kernel(float* __restrict__ chol, int k0) {
    const int m = blockIdx.y;
    float* __restrict__ A = chol + (size_t)m * DD;
    __shared__ float Ld[64][68];
    __shared__ float rd[64];
    const int t = threadIdx.x;

    for (int e = t; e < 1024; e += 256) {
        int r = e >> 4, q = e & 15;
        *(float4*)&Ld[r][q * 4] = *(const float4*)(A + (size_t)(k0 + r) * DIM + k0 + q * 4);
    }
    __syncthreads();
    if (t < 64) rd[t] = 1.f / Ld[t][t];
    __syncthreads();

    const int r = k0 + 64 + blockIdx.x * 256 + t;
    if (r >= DIM) return;

    float xr[64];
    float4* xv = (float4*)xr;
    const float4* sp = (const float4*)(A + (size_t)r * DIM + k0);
#pragma unroll
    for (int u = 0; u < 16; ++u) xv[u] = sp[u];

#pragma unroll
    for (int kk = 0; kk < 64; ++kk) {
        float s0 = 0.f, s1 = 0.f;
        const float* lrow = &Ld[kk][0];
#pragma unroll
        for (int u = 0; u + 7 < kk; u += 8) {
            float4 l0 = *(const float4*)(lrow + u);
            float4 l1 = *(const float4*)(lrow + u + 4);
            s0 += xr[u] * l0.x + xr[u + 1] * l0.y + xr[u + 2] * l0.z + xr[u + 3] * l0.w;
            s1 += xr[u + 4] * l1.x + xr[u + 5] * l1.y + xr[u + 6] * l1.z + xr[u + 7] * l1.w;
        }
#pragma unroll
        for (int u = kk & ~7; u < kk; ++u) s0 += xr[u] * lrow[u];
        xr[kk] = (xr[kk] - (s0 + s1)) * rd[kk];
    }

    float4* dp = (float4*)(A + (size_t)r * DIM + k0);
#pragma unroll
    for (int u = 0; u < 16; ++u) dp[u] = xv[u];
}

__global__ __launch_bounds__(256) void syrk_kernel(float* __restrict__ chol, int k0) {
    const int m = blockIdx.y;
    float* __restrict__ A = chol + (size_t)m * DD;
    const int st = k0 + 64;
    int x = blockIdx.x;
    int bi = 0;
    while ((bi + 1) * (bi + 2) / 2 <= x) ++bi;
    const int bj = x - bi * (bi + 1) / 2;
    const int ra = st + bi * 64, ca = st + bj * 64;

    __shared__ float PiT[64][68];
    __shared__ float PjT[64][68];
    const int t = threadIdx.x;

    for (int idx = t; idx < 1024; idx += 256) {
        int r = idx >> 4, f4 = idx & 15;
        float4 v = *(const float4*)(A + (size_t)(ra + r) * DIM + k0 + f4 * 4);
        PiT[f4 * 4 + 0][r] = v.x; PiT[f4 * 4 + 1][r] = v.y;
        PiT[f4 * 4 + 2][r] = v.z; PiT[f4 * 4 + 3][r] = v.w;
    }
    if (bj < bi) {
        for (int idx = t; idx < 1024; idx += 256) {
            int r = idx >> 4, f4 = idx & 15;
            float4 v = *(const float4*)(A + (size_t)(ca + r) * DIM + k0 + f4 * 4);
            PjT[f4 * 4 + 0][r] = v.x; PjT[f4 * 4 + 1][r] = v.y;
            PjT[f4 * 4 + 2][r] = v.z; PjT[f4 * 4 + 3][r] = v.w;
        }
    }
    __syncthreads();

    float (*Pj)[68] = (bj == bi) ? PiT : PjT;
    const int r0 = (t >> 4) * 4;
    const int c0 = (t & 15) * 4;
    float acc[4][4] = {};
#pragma unroll
    for (int u = 0; u < 64; ++u) {
        float4 a4 = *(const float4*)&PiT[u][r0];
        float4 b4 = *(const float4*)&Pj[u][c0];
        float a_[4] = {a4.x, a4.y, a4.z, a4.w};
        float b_[4] = {b4.x, b4.y, b4.z, b4.w};
#pragma unroll
        for (int i = 0; i < 4; ++i)
#pragma unroll
            for (int j = 0; j < 4; ++j)
                acc[i][j] = fmaf(a_[i], b_[j], acc[i][j]);
    }

#pragma unroll
    for (int i = 0; i < 4; ++i) {
        float* p = A + (size_t)(ra + r0 + i) * DIM + ca + c0;
        float4 v = *(const float4*)p;
        v.x -= acc[i][0]; v.y -= acc[i][1]; v.z -= acc[i][2]; v.w -= acc[i][3];
        *(float4*)p = v;
    }
}

// ---------------- final scalar combine ----------------

__global__ void finalize_kernel(const float* __restrict__ logdets,
                                const int* __restrict__ counts,
                                unsigned int* __restrict__ out) {
    if (threadIdx.x == 0 && blockIdx.x == 0) {
        const float nf = 32768.f;
        float compZ = 0.f, compH = 0.f, pc = 0.f;
        for (int j = 0; j < NCLS; ++j) {
            float c = (float)counts[j];
            float trPi = c + 1e-8f;
            compZ += trPi / (2.f * nf) * logdets[2 + j];
            compH += trPi / (2.f * nf) * logdets[12 + j];
            pc += -(logdets[22 + j] * 0.5f
                    - trPi / (4.f * c) * (logdets[2 + j] + logdets[12 + j]));
        }
        float loss_z = -(logdets[0] * 0.5f - compZ);
        float loss_h = -(logdets[1] * 0.5f - compH);
        float v = loss_z + loss_h + pc;
        unsigned int x = __float_as_uint(v);
        unsigned int r = (x + 0x7fffu + ((x >> 16) & 1u)) >> 16;  // rne bf16
        out[0] = (r << 16) | r;
    }
}

// ---------------- launch ----------------

extern "C" void kernel_launch(void* const* d_in, const int* in_sizes, int n_in,
                              void* d_out, int out_size, void* d_ws, size_t ws_size,
                              hipStream_t stream) {
    const float* Z  = (const float*)d_in[0];
    const float* Zb = (const float*)d_in[1];
    const int* lab  = (const int*)d_in[2];

    float* chol = (float*)d_ws;                         // 32 matrices, 4 MiB each
    unsigned short* Ht = (unsigned short*)(chol + 32ull * DD);
    unsigned short* Lt = Ht + (size_t)DIM * PSTRIDE;    // 64.6 MB each
    int* order   = (int*)(Lt + (size_t)DIM * PSTRIDE);
    int* counts  = order + NPOS;
    int* cursor  = counts + 16;
    int* offs    = cursor + 16;
    float* logdets = (float*)(offs + 16);

    init_small_kernel<<<1, 64, 0, stream>>>(counts, cursor, logdets);
    hipMemsetAsync(order, 0xff, NPOS * sizeof(int), stream);   // order[p] = -1 (pads)
    hist_kernel<<<128, 256, 0, stream>>>(lab, counts);
    offs_kernel<<<1, 64, 0, stream>>>(counts, offs);
    scatter_kernel<<<128, 256, 0, stream>>>(lab, offs, cursor, order);

    // Z half: convert+transpose+split, then MFMA grams into slots 2..11
    preconv_kernel<<<dim3(NPOS / 64, DIM / 64), 256, 0, stream>>>(Z, order, Ht, Lt);
    gram_mfma_kernel<<<dim3(36, NCLS), 256, 0, stream>>>(Ht, Lt, counts, offs, chol + 2ull * DD);

    // Zb half reuses the same Ht/Lt buffers (stream serializes)
    preconv_kernel<<<dim3(NPOS / 64, DIM / 64), 256, 0, stream>>>(Zb, order, Ht, Lt);
    gram_mfma_kernel<<<dim3(36, NCLS), 256, 0, stream>>>(Ht, Lt, counts, offs, chol + 12ull * DD);

    build_kernel<<<4096, 256, 0, stream>>>(chol, counts);

    for (int s = 0; s < 16; ++s) {
        const int k0 = s * 64;
        diag_kernel<<<32, 256, 0, stream>>>(chol, logdets, k0);
        const int nr = DIM - k0 - 64;
        if (nr > 0) {
            const int bpm = (nr + 255) / 256;
            trsm_kernel<<<dim3(bpm, 32), 256, 0, stream>>>(chol, k0);
            const int nt = nr / 64;
            const int tiles = nt * (nt + 1) / 2;
            syrk_kernel<<<dim3(tiles, 32), 256, 0, stream>>>(chol, k0);
        }
    }

    finalize_kernel<<<1, 64, 0, stream>>>(logdets, counts, (unsigned int*)d_out);
}